// Round 1
// baseline (3632.883 us; speedup 1.0000x reference)
//
#include <hip/hip_runtime.h>
#include <math.h>

#define NN 100000
#define NE 3200000
#define NF 512
#define NH 256
#define NC 64
#define KSTEPS 10
#define NB 391   // ceil(NN/256)

typedef _Float16 half4 __attribute__((ext_vector_type(4)));

// ---------------- graph prep ----------------

__global__ __launch_bounds__(256) void init_deg_k(float* deg) {
  int i = blockIdx.x * 256 + threadIdx.x;
  if (i < NN) deg[i] = 1.0f;   // self-loop
}

__global__ __launch_bounds__(256) void accum_deg_k(const int* __restrict__ dst, float* deg) {
  int e = blockIdx.x * 256 + threadIdx.x;
  if (e < NE) atomicAdd(&deg[dst[e]], 1.0f);
}

__global__ __launch_bounds__(256) void scan1_k(const float* __restrict__ deg, int* partial, int* bsums) {
  __shared__ int s[256];
  int tid = threadIdx.x;
  int i = blockIdx.x * 256 + tid;
  int c = (i < NN) ? (int)deg[i] : 0;
  s[tid] = c;
  __syncthreads();
  int v = c;
  for (int off = 1; off < 256; off <<= 1) {
    int t = (tid >= off) ? s[tid - off] : 0;
    __syncthreads();
    v += t;
    s[tid] = v;
    __syncthreads();
  }
  if (i < NN) partial[i] = v - c;     // exclusive prefix within block
  if (tid == 255) bsums[blockIdx.x] = v;
}

__global__ __launch_bounds__(512) void scan2_k(const int* __restrict__ bs, int* boffs) {
  __shared__ int s[512];
  int tid = threadIdx.x;
  int c = (tid < NB) ? bs[tid] : 0;
  s[tid] = c;
  __syncthreads();
  int v = c;
  for (int off = 1; off < 512; off <<= 1) {
    int t = (tid >= off) ? s[tid - off] : 0;
    __syncthreads();
    v += t;
    s[tid] = v;
    __syncthreads();
  }
  if (tid < NB) boffs[tid] = v - c;
}

__global__ __launch_bounds__(256) void scan3_k(const int* __restrict__ partial, const int* __restrict__ boffs,
                                               int* row_ptr, int* fill) {
  int i = blockIdx.x * 256 + threadIdx.x;
  if (i < NN) {
    int r = partial[i] + boffs[blockIdx.x];
    row_ptr[i] = r;
    fill[i] = r;
  }
  if (i == 0) row_ptr[NN] = NE + NN;
}

__global__ __launch_bounds__(256) void dinv_k(float* deg) {
  int i = blockIdx.x * 256 + threadIdx.x;
  if (i < NN) deg[i] = rsqrtf(deg[i]);   // deg >= 1 always (self-loop)
}

__global__ __launch_bounds__(256) void fill_k(const int* __restrict__ srcI, const int* __restrict__ dstI,
                                              const float* __restrict__ dinv, int* fill,
                                              int* srcS, float* wS) {
  int e = blockIdx.x * 256 + threadIdx.x;
  if (e >= NE + NN) return;
  int s, d;
  if (e < NE) { s = srcI[e]; d = dstI[e]; }
  else        { s = e - NE;  d = s; }
  float w = dinv[s] * dinv[d];
  int pos = atomicAdd(&fill[d], 1);
  srcS[pos] = s;
  wS[pos] = w;
}

// ---------------- fused 2-layer MLP ----------------
// block = 512 threads, 64 nodes/block. Hidden activations kept in LDS as fp16.
// LDS: As 8704 + Ws 16384 + Hs 36864 = 61952 B (<= 64KB static limit, 2 blocks/CU)

__global__ __launch_bounds__(512) void mlp_k(const float* __restrict__ x, const float* __restrict__ W1,
                                             const float* __restrict__ b1, const float* __restrict__ W2,
                                             const float* __restrict__ b2, float* __restrict__ h0) {
  __shared__ float As[32][68];        // x tile, transposed [k][node]
  __shared__ float Ws[32][128];       // W1 tile [k][h]
  __shared__ _Float16 Hs[256][72];    // relu(hidden), transposed [h][node]
  const int t = threadIdx.x;
  const int node0 = blockIdx.x * 64;
  const int tx = t & 31;   // phase1: hidden quad | phase2: class pair
  const int ty = t >> 5;   // node quad (0..15)

  // ---- phase 1: H = relu(x @ W1 + b1), two 128-wide hidden chunks ----
  for (int hc = 0; hc < 2; ++hc) {
    float acc[4][4] = {};
    for (int kk = 0; kk < NF; kk += 32) {
      { // stage x tile 64x32 (transposed into As)
        int r = t >> 3;            // 0..63 node
        int c = (t & 7) << 2;      // 0..28 k
        int gr = node0 + r;
        float4 v = make_float4(0.f, 0.f, 0.f, 0.f);
        if (gr < NN) v = *(const float4*)&x[(size_t)gr * NF + kk + c];
        As[c + 0][r] = v.x; As[c + 1][r] = v.y; As[c + 2][r] = v.z; As[c + 3][r] = v.w;
      }
      { // stage W1 tile 32x128
        int r = t >> 4;            // 0..31 k
        int c = (t & 15) << 3;     // 0..120 h
        const float* wp = &W1[(size_t)(kk + r) * NH + hc * 128 + c];
        float4 v0 = *(const float4*)wp;
        float4 v1 = *(const float4*)(wp + 4);
        *(float4*)&Ws[r][c]     = v0;
        *(float4*)&Ws[r][c + 4] = v1;
      }
      __syncthreads();
      #pragma unroll
      for (int k = 0; k < 32; ++k) {
        float4 a = *(const float4*)&As[k][ty << 2];
        float4 b = *(const float4*)&Ws[k][tx << 2];
        acc[0][0] += a.x * b.x; acc[0][1] += a.x * b.y; acc[0][2] += a.x * b.z; acc[0][3] += a.x * b.w;
        acc[1][0] += a.y * b.x; acc[1][1] += a.y * b.y; acc[1][2] += a.y * b.z; acc[1][3] += a.y * b.w;
        acc[2][0] += a.z * b.x; acc[2][1] += a.z * b.y; acc[2][2] += a.z * b.z; acc[2][3] += a.z * b.w;
        acc[3][0] += a.w * b.x; acc[3][1] += a.w * b.y; acc[3][2] += a.w * b.z; acc[3][3] += a.w * b.w;
      }
      __syncthreads();
    }
    #pragma unroll
    for (int j = 0; j < 4; ++j) {
      float bb = b1[hc * 128 + (tx << 2) + j];
      #pragma unroll
      for (int i = 0; i < 4; ++i) {
        float v = acc[i][j] + bb;
        Hs[hc * 128 + (tx << 2) + j][(ty << 2) + i] = (_Float16)(v > 0.f ? v : 0.f);
      }
    }
  }
  __syncthreads();

  // ---- phase 2: h0 = H @ W2 + b2 (64 nodes x 64 classes) ----
  {
    float acc2[4][2] = {};
    #pragma unroll 4
    for (int k = 0; k < NH; ++k) {
      half4 ah = *(const half4*)&Hs[k][ty << 2];
      float2 b = *(const float2*)&W2[k * NC + (tx << 1)];
      float a0 = (float)ah.x, a1 = (float)ah.y, a2 = (float)ah.z, a3 = (float)ah.w;
      acc2[0][0] += a0 * b.x; acc2[0][1] += a0 * b.y;
      acc2[1][0] += a1 * b.x; acc2[1][1] += a1 * b.y;
      acc2[2][0] += a2 * b.x; acc2[2][1] += a2 * b.y;
      acc2[3][0] += a3 * b.x; acc2[3][1] += a3 * b.y;
    }
    #pragma unroll
    for (int i = 0; i < 4; ++i) {
      int n = node0 + (ty << 2) + i;
      if (n < NN) {
        #pragma unroll
        for (int j = 0; j < 2; ++j) {
          int c = (tx << 1) + j;
          h0[(size_t)n * NC + c] = acc2[i][j] + b2[c];
        }
      }
    }
  }
}

// ---------------- APPNP propagation step ----------------
// one wave per node; lane = feature (NC == 64 == wave width)

__global__ __launch_bounds__(256) void appnp_k(const float* __restrict__ h_in, const float* __restrict__ h0,
                                               float* __restrict__ h_out,
                                               const int* __restrict__ row_ptr, const int* __restrict__ srcS,
                                               const float* __restrict__ wS) {
  int lane = threadIdx.x & 63;
  int node = blockIdx.x * 4 + (threadIdx.x >> 6);
  node = __builtin_amdgcn_readfirstlane(node);   // wave-uniform -> scalar loads
  if (node >= NN) return;
  int beg = row_ptr[node];
  int end = row_ptr[node + 1];
  float acc = 0.f;
  for (int e = beg; e < end; ++e) {
    int s = srcS[e];          // wave-uniform s_load
    float w = wS[e];          // wave-uniform s_load
    acc += w * h_in[(size_t)s * NC + lane];   // coalesced 256B gather
  }
  int o = node * NC + lane;
  h_out[o] = 0.9f * acc + 0.1f * h0[o];
}

// ---------------- log_softmax ----------------

__global__ __launch_bounds__(256) void lsm_k(const float* __restrict__ h, float* __restrict__ out) {
  int lane = threadIdx.x & 63;
  int node = blockIdx.x * 4 + (threadIdx.x >> 6);
  if (node >= NN) return;
  float v = h[node * NC + lane];
  float m = v;
  #pragma unroll
  for (int off = 32; off > 0; off >>= 1) m = fmaxf(m, __shfl_xor(m, off, 64));
  float e = expf(v - m);
  float s = e;
  #pragma unroll
  for (int off = 32; off > 0; off >>= 1) s += __shfl_xor(s, off, 64);
  out[node * NC + lane] = (v - m) - logf(s);
}

// ---------------- launch ----------------

extern "C" void kernel_launch(void* const* d_in, const int* in_sizes, int n_in,
                              void* d_out, int out_size, void* d_ws, size_t ws_size,
                              hipStream_t stream) {
  (void)in_sizes; (void)n_in; (void)out_size; (void)ws_size;
  const float* x  = (const float*)d_in[0];
  const int*   ei = (const int*)d_in[1];
  const float* W1 = (const float*)d_in[2];
  const float* b1 = (const float*)d_in[3];
  const float* W2 = (const float*)d_in[4];
  const float* b2 = (const float*)d_in[5];
  float* out = (float*)d_out;

  const int* srcI = ei;        // edge_index[0] = message source
  const int* dstI = ei + NE;   // edge_index[1] = aggregation target

  char* p = (char*)d_ws;
  auto carve = [&](size_t bytes) -> void* {
    void* q = (void*)p;
    p += (bytes + 255) & ~(size_t)255;
    return q;
  };
  float* h0      = (float*)carve((size_t)NN * NC * 4);
  float* hA      = (float*)carve((size_t)NN * NC * 4);
  float* hB      = (float*)carve((size_t)NN * NC * 4);
  float* deg     = (float*)carve((size_t)NN * 4);        // becomes dinv in-place
  int*   row_ptr = (int*)carve((size_t)(NN + 1) * 4);
  int*   fill    = (int*)carve((size_t)NN * 4);
  int*   partial = (int*)carve((size_t)NN * 4);
  int*   bsums   = (int*)carve((size_t)NB * 4);
  int*   boffs   = (int*)carve((size_t)NB * 4);
  int*   srcS    = (int*)carve((size_t)(NE + NN) * 4);
  float* wS      = (float*)carve((size_t)(NE + NN) * 4);

  init_deg_k <<<NB, 256, 0, stream>>>(deg);
  accum_deg_k<<<(NE + 255) / 256, 256, 0, stream>>>(dstI, deg);
  scan1_k    <<<NB, 256, 0, stream>>>(deg, partial, bsums);
  scan2_k    <<<1, 512, 0, stream>>>(bsums, boffs);
  scan3_k    <<<NB, 256, 0, stream>>>(partial, boffs, row_ptr, fill);
  dinv_k     <<<NB, 256, 0, stream>>>(deg);
  fill_k     <<<(NE + NN + 255) / 256, 256, 0, stream>>>(srcI, dstI, deg, fill, srcS, wS);
  mlp_k      <<<(NN + 63) / 64, 512, 0, stream>>>(x, W1, b1, W2, b2, h0);

  const float* hin = h0;
  float* bufs[2] = { hA, hB };
  for (int it = 0; it < KSTEPS; ++it) {
    float* ho = bufs[it & 1];
    appnp_k<<<NN / 4, 256, 0, stream>>>(hin, h0, ho, row_ptr, srcS, wS);
    hin = ho;
  }
  lsm_k<<<NN / 4, 256, 0, stream>>>(hin, out);
}

// Round 2
// 2050.999 us; speedup vs baseline: 1.7713x; 1.7713x over previous
//
#include <hip/hip_runtime.h>
#include <math.h>

#define NN 100000
#define NE 3200000
#define NF 512
#define NH 256
#define NC 64
#define KSTEPS 10
#define NB 391   // ceil(NN/256)

typedef _Float16 half8 __attribute__((ext_vector_type(8)));
typedef float f32x4 __attribute__((ext_vector_type(4)));

// ---------------- graph prep ----------------

__global__ __launch_bounds__(256) void init_deg_k(float* deg) {
  int i = blockIdx.x * 256 + threadIdx.x;
  if (i < NN) deg[i] = 1.0f;   // self-loop
}

__global__ __launch_bounds__(256) void accum_deg_k(const int* __restrict__ dst, float* deg) {
  int e = blockIdx.x * 256 + threadIdx.x;
  if (e < NE) atomicAdd(&deg[dst[e]], 1.0f);
}

__global__ __launch_bounds__(256) void scan1_k(const float* __restrict__ deg, int* partial, int* bsums) {
  __shared__ int s[256];
  int tid = threadIdx.x;
  int i = blockIdx.x * 256 + tid;
  int c = (i < NN) ? (int)deg[i] : 0;
  s[tid] = c;
  __syncthreads();
  int v = c;
  for (int off = 1; off < 256; off <<= 1) {
    int t = (tid >= off) ? s[tid - off] : 0;
    __syncthreads();
    v += t;
    s[tid] = v;
    __syncthreads();
  }
  if (i < NN) partial[i] = v - c;     // exclusive prefix within block
  if (tid == 255) bsums[blockIdx.x] = v;
}

__global__ __launch_bounds__(512) void scan2_k(const int* __restrict__ bs, int* boffs) {
  __shared__ int s[512];
  int tid = threadIdx.x;
  int c = (tid < NB) ? bs[tid] : 0;
  s[tid] = c;
  __syncthreads();
  int v = c;
  for (int off = 1; off < 512; off <<= 1) {
    int t = (tid >= off) ? s[tid - off] : 0;
    __syncthreads();
    v += t;
    s[tid] = v;
    __syncthreads();
  }
  if (tid < NB) boffs[tid] = v - c;
}

__global__ __launch_bounds__(256) void scan3_k(const int* __restrict__ partial, const int* __restrict__ boffs,
                                               int* row_ptr, int* fill) {
  int i = blockIdx.x * 256 + threadIdx.x;
  if (i < NN) {
    int r = partial[i] + boffs[blockIdx.x];
    row_ptr[i] = r;
    fill[i] = r;
  }
  if (i == 0) row_ptr[NN] = NE + NN;
}

__global__ __launch_bounds__(256) void dinv_k(float* deg) {
  int i = blockIdx.x * 256 + threadIdx.x;
  if (i < NN) deg[i] = rsqrtf(deg[i]);   // deg >= 1 always (self-loop)
}

__global__ __launch_bounds__(256) void fill_k(const int* __restrict__ srcI, const int* __restrict__ dstI,
                                              const float* __restrict__ dinv, int* fill,
                                              int* srcS, float* wS) {
  int e = blockIdx.x * 256 + threadIdx.x;
  if (e >= NE + NN) return;
  int s, d;
  if (e < NE) { s = srcI[e]; d = dstI[e]; }
  else        { s = e - NE;  d = s; }
  float w = dinv[s] * dinv[d];
  int pos = atomicAdd(&fill[d], 1);
  srcS[pos] = s;
  wS[pos] = w;
}

// ---------------- weight transpose + fp16 convert ----------------

__global__ __launch_bounds__(256) void cvtW1T_k(const float* __restrict__ W1, _Float16* __restrict__ W1T) {
  int t = blockIdx.x * 256 + threadIdx.x;            // 131072
  int n = t >> 9, k = t & 511;
  W1T[t] = (_Float16)W1[k * NH + n];                 // W1T[n][k] = W1[k][n]
}

__global__ __launch_bounds__(256) void cvtW2T_k(const float* __restrict__ W2, _Float16* __restrict__ W2T) {
  int t = blockIdx.x * 256 + threadIdx.x;            // 16384
  int n = t >> 8, k = t & 255;
  W2T[t] = (_Float16)W2[k * NC + n];                 // W2T[n][k] = W2[k][n]
}

// ---------------- fused 2-layer MLP via f16 MFMA ----------------
// block = 256 threads (4 waves), 64 nodes/block.
// GEMM1: 64x256 tile over K=512 (16x16x32 MFMA, wave w owns cols [64w,64w+64))
// hidden relu'd into LDS fp16, then GEMM2: 64x64 over K=256 (wave w owns cols [16w,16w+16))
// LDS: union( As[64][40]+Bs[256][40] = 25600 B , Hs[64][264] = 33792 B ) = 33792 B

__global__ __launch_bounds__(256) void mlp_k(const float* __restrict__ x, const _Float16* __restrict__ W1T,
                                             const float* __restrict__ b1, const _Float16* __restrict__ W2T,
                                             const float* __restrict__ b2, _Float16* __restrict__ h0) {
  __shared__ _Float16 smem[16896];          // 33792 B
  _Float16* As = smem;                      // [64][40]
  _Float16* Bs = smem + 64 * 40;            // [256][40]
  _Float16* Hs = smem;                      // [64][264] (reuses As/Bs space)

  const int t    = threadIdx.x;
  const int wave = t >> 6;
  const int lane = t & 63;
  const int l15  = lane & 15;
  const int q    = lane >> 4;
  const int m0   = blockIdx.x * 64;

  f32x4 acc[4][4] = {};

  for (int kk = 0; kk < NF; kk += 32) {
    __syncthreads();                        // prev-iter LDS reads done before overwrite
    { // stage A: x[m0..m0+64)[kk..kk+32) -> fp16 As
      int row = t >> 2;
      int kq  = (t & 3) << 3;
      int gr  = m0 + row;
      float4 v0 = make_float4(0.f, 0.f, 0.f, 0.f), v1 = v0;
      if (gr < NN) {
        const float* xp = &x[(size_t)gr * NF + kk + kq];
        v0 = *(const float4*)xp;
        v1 = *(const float4*)(xp + 4);
      }
      half8 hv;
      hv[0] = (_Float16)v0.x; hv[1] = (_Float16)v0.y; hv[2] = (_Float16)v0.z; hv[3] = (_Float16)v0.w;
      hv[4] = (_Float16)v1.x; hv[5] = (_Float16)v1.y; hv[6] = (_Float16)v1.z; hv[7] = (_Float16)v1.w;
      *(half8*)&As[row * 40 + kq] = hv;
    }
    // stage B: W1T[0..256)[kk..kk+32) -> Bs
    #pragma unroll
    for (int i = 0; i < 4; ++i) {
      int idx = t + (i << 8);
      int n   = idx >> 2;
      int kq  = (idx & 3) << 3;
      *(half8*)&Bs[n * 40 + kq] = *(const half8*)&W1T[(size_t)n * NF + kk + kq];
    }
    __syncthreads();
    half8 af[4], bf[4];
    #pragma unroll
    for (int mi = 0; mi < 4; ++mi) af[mi] = *(half8*)&As[(mi * 16 + l15) * 40 + q * 8];
    #pragma unroll
    for (int ni = 0; ni < 4; ++ni) bf[ni] = *(half8*)&Bs[(wave * 64 + ni * 16 + l15) * 40 + q * 8];
    #pragma unroll
    for (int mi = 0; mi < 4; ++mi)
      #pragma unroll
      for (int ni = 0; ni < 4; ++ni)
        acc[mi][ni] = __builtin_amdgcn_mfma_f32_16x16x32_f16(af[mi], bf[ni], acc[mi][ni], 0, 0, 0);
  }
  __syncthreads();   // all As/Bs reads complete -> safe to reuse as Hs

  // epilogue 1: bias + relu -> Hs fp16  (C/D: col=lane&15, row=q*4+reg)
  #pragma unroll
  for (int mi = 0; mi < 4; ++mi) {
    #pragma unroll
    for (int ni = 0; ni < 4; ++ni) {
      int ch = wave * 64 + ni * 16 + l15;
      float bb = b1[ch];
      #pragma unroll
      for (int r = 0; r < 4; ++r) {
        int m = mi * 16 + q * 4 + r;
        float v = acc[mi][ni][r] + bb;
        Hs[m * 264 + ch] = (_Float16)(v > 0.f ? v : 0.f);
      }
    }
  }
  __syncthreads();

  // GEMM2: h0[64x64] = Hs[64x256] @ W2 (+b2); wave w -> cols [16w, 16w+16)
  f32x4 acc2[4] = {};
  for (int kt = 0; kt < 8; ++kt) {
    half8 bf2 = *(const half8*)&W2T[(size_t)(wave * 16 + l15) * NH + kt * 32 + q * 8];
    #pragma unroll
    for (int mi = 0; mi < 4; ++mi) {
      half8 af2 = *(half8*)&Hs[(mi * 16 + l15) * 264 + kt * 32 + q * 8];
      acc2[mi] = __builtin_amdgcn_mfma_f32_16x16x32_f16(af2, bf2, acc2[mi], 0, 0, 0);
    }
  }
  int c = wave * 16 + l15;
  float bb2 = b2[c];
  #pragma unroll
  for (int mi = 0; mi < 4; ++mi)
    #pragma unroll
    for (int r = 0; r < 4; ++r) {
      int m = m0 + mi * 16 + q * 4 + r;
      if (m < NN) h0[(size_t)m * NC + c] = (_Float16)(acc2[mi][r] + bb2);
    }
}

// ---------------- APPNP propagation step (fp16 h) ----------------
// one wave per node; lane = feature (NC == 64 == wave width)

__global__ __launch_bounds__(256) void appnp_k(const _Float16* __restrict__ h_in, const _Float16* __restrict__ h0,
                                               _Float16* __restrict__ h_out,
                                               const int* __restrict__ row_ptr, const int* __restrict__ srcS,
                                               const float* __restrict__ wS) {
  int lane = threadIdx.x & 63;
  int node = blockIdx.x * 4 + (threadIdx.x >> 6);
  node = __builtin_amdgcn_readfirstlane(node);   // wave-uniform -> scalar loads
  int beg = row_ptr[node];
  int end = row_ptr[node + 1];
  float acc0 = 0.f, acc1 = 0.f;
  int e = beg;
  for (; e + 2 <= end; e += 2) {
    int s0 = srcS[e];
    int s1 = srcS[e + 1];
    float w0 = wS[e];
    float w1 = wS[e + 1];
    acc0 += w0 * (float)h_in[(size_t)s0 * NC + lane];
    acc1 += w1 * (float)h_in[(size_t)s1 * NC + lane];
  }
  if (e < end) acc0 += wS[e] * (float)h_in[(size_t)srcS[e] * NC + lane];
  int o = node * NC + lane;
  h_out[o] = (_Float16)(0.9f * (acc0 + acc1) + 0.1f * (float)h0[o]);
}

// ---------------- log_softmax ----------------

__global__ __launch_bounds__(256) void lsm_k(const _Float16* __restrict__ h, float* __restrict__ out) {
  int lane = threadIdx.x & 63;
  int node = blockIdx.x * 4 + (threadIdx.x >> 6);
  if (node >= NN) return;
  float v = (float)h[node * NC + lane];
  float m = v;
  #pragma unroll
  for (int off = 32; off > 0; off >>= 1) m = fmaxf(m, __shfl_xor(m, off, 64));
  float e = expf(v - m);
  float s = e;
  #pragma unroll
  for (int off = 32; off > 0; off >>= 1) s += __shfl_xor(s, off, 64);
  out[node * NC + lane] = (v - m) - logf(s);
}

// ---------------- launch ----------------

extern "C" void kernel_launch(void* const* d_in, const int* in_sizes, int n_in,
                              void* d_out, int out_size, void* d_ws, size_t ws_size,
                              hipStream_t stream) {
  (void)in_sizes; (void)n_in; (void)out_size; (void)ws_size;
  const float* x  = (const float*)d_in[0];
  const int*   ei = (const int*)d_in[1];
  const float* W1 = (const float*)d_in[2];
  const float* b1 = (const float*)d_in[3];
  const float* W2 = (const float*)d_in[4];
  const float* b2 = (const float*)d_in[5];
  float* out = (float*)d_out;

  const int* srcI = ei;        // edge_index[0] = message source
  const int* dstI = ei + NE;   // edge_index[1] = aggregation target

  char* p = (char*)d_ws;
  auto carve = [&](size_t bytes) -> void* {
    void* q = (void*)p;
    p += (bytes + 255) & ~(size_t)255;
    return q;
  };
  _Float16* h0   = (_Float16*)carve((size_t)NN * NC * 2);
  _Float16* hA   = (_Float16*)carve((size_t)NN * NC * 2);
  _Float16* hB   = (_Float16*)carve((size_t)NN * NC * 2);
  _Float16* W1T  = (_Float16*)carve((size_t)NH * NF * 2);
  _Float16* W2T  = (_Float16*)carve((size_t)NC * NH * 2);
  float* deg     = (float*)carve((size_t)NN * 4);        // becomes dinv in-place
  int*   row_ptr = (int*)carve((size_t)(NN + 1) * 4);
  int*   fill    = (int*)carve((size_t)NN * 4);
  int*   partial = (int*)carve((size_t)NN * 4);
  int*   bsums   = (int*)carve((size_t)NB * 4);
  int*   boffs   = (int*)carve((size_t)NB * 4);
  int*   srcS    = (int*)carve((size_t)(NE + NN) * 4);
  float* wS      = (float*)carve((size_t)(NE + NN) * 4);

  init_deg_k <<<NB, 256, 0, stream>>>(deg);
  accum_deg_k<<<(NE + 255) / 256, 256, 0, stream>>>(dstI, deg);
  scan1_k    <<<NB, 256, 0, stream>>>(deg, partial, bsums);
  scan2_k    <<<1, 512, 0, stream>>>(bsums, boffs);
  scan3_k    <<<NB, 256, 0, stream>>>(partial, boffs, row_ptr, fill);
  dinv_k     <<<NB, 256, 0, stream>>>(deg);
  fill_k     <<<(NE + NN + 255) / 256, 256, 0, stream>>>(srcI, dstI, deg, fill, srcS, wS);
  cvtW1T_k   <<<(NH * NF) / 256, 256, 0, stream>>>(W1, W1T);
  cvtW2T_k   <<<(NC * NH) / 256, 256, 0, stream>>>(W2, W2T);
  mlp_k      <<<(NN + 63) / 64, 256, 0, stream>>>(x, W1T, b1, W2T, b2, h0);

  const _Float16* hin = h0;
  _Float16* bufs[2] = { hA, hB };
  for (int it = 0; it < KSTEPS; ++it) {
    _Float16* ho = bufs[it & 1];
    appnp_k<<<NN / 4, 256, 0, stream>>>(hin, h0, ho, row_ptr, srcS, wS);
    hin = ho;
  }
  lsm_k<<<NN / 4, 256, 0, stream>>>(hin, out);
}

// Round 3
// 1397.048 us; speedup vs baseline: 2.6004x; 1.4681x over previous
//
#include <hip/hip_runtime.h>
#include <math.h>

#define NN 100000
#define NE 3200000
#define NF 512
#define NH 256
#define NC 64
#define KSTEPS 10
#define NB 391   // ceil(NN/256)

typedef _Float16 half8 __attribute__((ext_vector_type(8)));
typedef float f32x4 __attribute__((ext_vector_type(4)));

// ---------------- graph prep ----------------

__global__ __launch_bounds__(256) void init_deg_k(float* deg) {
  int i = blockIdx.x * 256 + threadIdx.x;
  if (i < NN) deg[i] = 1.0f;   // self-loop
}

__global__ __launch_bounds__(256) void accum_deg_k(const int* __restrict__ dst, float* deg) {
  int e = blockIdx.x * 256 + threadIdx.x;
  if (e < NE) atomicAdd(&deg[dst[e]], 1.0f);
}

// padded real-edge count per node: roundup(deg-1, 8)
__device__ __forceinline__ int padcnt(float degv) {
  return (((int)degv - 1) + 7) & ~7;
}

__global__ __launch_bounds__(256) void scan1_k(const float* __restrict__ deg, int* partial, int* bsums) {
  __shared__ int s[256];
  int tid = threadIdx.x;
  int i = blockIdx.x * 256 + tid;
  int c = (i < NN) ? padcnt(deg[i]) : 0;
  s[tid] = c;
  __syncthreads();
  int v = c;
  for (int off = 1; off < 256; off <<= 1) {
    int t = (tid >= off) ? s[tid - off] : 0;
    __syncthreads();
    v += t;
    s[tid] = v;
    __syncthreads();
  }
  if (i < NN) partial[i] = v - c;     // exclusive prefix within block
  if (tid == 255) bsums[blockIdx.x] = v;
}

__global__ __launch_bounds__(512) void scan2_k(const int* __restrict__ bs, int* boffs) {
  __shared__ int s[512];
  int tid = threadIdx.x;
  int c = (tid < NB) ? bs[tid] : 0;
  s[tid] = c;
  __syncthreads();
  int v = c;
  for (int off = 1; off < 512; off <<= 1) {
    int t = (tid >= off) ? s[tid - off] : 0;
    __syncthreads();
    v += t;
    s[tid] = v;
    __syncthreads();
  }
  if (tid < NB) boffs[tid] = v - c;
}

__global__ __launch_bounds__(256) void scan3_k(const int* __restrict__ partial, const int* __restrict__ boffs,
                                               const float* __restrict__ deg, int* row_ptr, int* fill) {
  int i = blockIdx.x * 256 + threadIdx.x;
  if (i < NN) {
    int r = partial[i] + boffs[blockIdx.x];
    row_ptr[i] = r;
    fill[i] = r;
    if (i == NN - 1) row_ptr[NN] = r + padcnt(deg[i]);
  }
}

// dinv + sqrt(deg) + 0.9/deg
__global__ __launch_bounds__(256) void dinv_k(const float* __restrict__ deg, float* dinv, float* dsqrt, float* amul) {
  int i = blockIdx.x * 256 + threadIdx.x;
  if (i < NN) {
    float d = deg[i];                 // >= 1 always
    dinv[i]  = rsqrtf(d);
    dsqrt[i] = sqrtf(d);
    amul[i]  = 0.9f / d;
  }
}

__global__ __launch_bounds__(256) void fill_k(const int* __restrict__ dstI, int* fill, const int* __restrict__ srcI,
                                              int* __restrict__ srcS) {
  int e = blockIdx.x * 256 + threadIdx.x;
  if (e >= NE) return;
  int s = srcI[e];
  int d = dstI[e];
  int pos = atomicAdd(&fill[d], 1);
  srcS[pos] = s;
}

// pad each row to its 8-aligned end with the zero-node index NN
__global__ __launch_bounds__(256) void pad_k(const int* __restrict__ fill, const int* __restrict__ row_ptr,
                                             int* __restrict__ srcS) {
  int d = blockIdx.x * 256 + threadIdx.x;
  if (d >= NN) return;
  int p = fill[d];
  int e = row_ptr[d + 1];
  for (; p < e; ++p) srcS[p] = NN;
}

// zero row NN of the three y-buffers (must run every launch: ws is re-poisoned)
__global__ __launch_bounds__(256) void zrow_k(_Float16* y0, _Float16* yA, _Float16* yB) {
  int t = threadIdx.x;
  if (t < 64)       y0[(size_t)NN * NC + t] = (_Float16)0.f;
  else if (t < 128) yA[(size_t)NN * NC + (t - 64)] = (_Float16)0.f;
  else if (t < 192) yB[(size_t)NN * NC + (t - 128)] = (_Float16)0.f;
}

// ---------------- weight transpose + fp16 convert ----------------

__global__ __launch_bounds__(256) void cvtW1T_k(const float* __restrict__ W1, _Float16* __restrict__ W1T) {
  int t = blockIdx.x * 256 + threadIdx.x;            // 131072
  int n = t >> 9, k = t & 511;
  W1T[t] = (_Float16)W1[k * NH + n];                 // W1T[n][k] = W1[k][n]
}

__global__ __launch_bounds__(256) void cvtW2T_k(const float* __restrict__ W2, _Float16* __restrict__ W2T) {
  int t = blockIdx.x * 256 + threadIdx.x;            // 16384
  int n = t >> 8, k = t & 255;
  W2T[t] = (_Float16)W2[k * NC + n];                 // W2T[n][k] = W2[k][n]
}

// ---------------- fused 2-layer MLP via f16 MFMA ----------------
// outputs y0 = dinv*h0 and c0 = 0.1*dinv*h0 (both fp16)

__global__ __launch_bounds__(256) void mlp_k(const float* __restrict__ x, const _Float16* __restrict__ W1T,
                                             const float* __restrict__ b1, const _Float16* __restrict__ W2T,
                                             const float* __restrict__ b2, const float* __restrict__ dinv,
                                             _Float16* __restrict__ y0, _Float16* __restrict__ c0) {
  __shared__ _Float16 smem[16896];          // 33792 B
  _Float16* As = smem;                      // [64][40]
  _Float16* Bs = smem + 64 * 40;            // [256][40]
  _Float16* Hs = smem;                      // [64][264] (reuses As/Bs space)

  const int t    = threadIdx.x;
  const int wave = t >> 6;
  const int lane = t & 63;
  const int l15  = lane & 15;
  const int q    = lane >> 4;
  const int m0   = blockIdx.x * 64;

  f32x4 acc[4][4] = {};

  for (int kk = 0; kk < NF; kk += 32) {
    __syncthreads();                        // prev-iter LDS reads done before overwrite
    { // stage A: x[m0..m0+64)[kk..kk+32) -> fp16 As
      int row = t >> 2;
      int kq  = (t & 3) << 3;
      int gr  = m0 + row;
      float4 v0 = make_float4(0.f, 0.f, 0.f, 0.f), v1 = v0;
      if (gr < NN) {
        const float* xp = &x[(size_t)gr * NF + kk + kq];
        v0 = *(const float4*)xp;
        v1 = *(const float4*)(xp + 4);
      }
      half8 hv;
      hv[0] = (_Float16)v0.x; hv[1] = (_Float16)v0.y; hv[2] = (_Float16)v0.z; hv[3] = (_Float16)v0.w;
      hv[4] = (_Float16)v1.x; hv[5] = (_Float16)v1.y; hv[6] = (_Float16)v1.z; hv[7] = (_Float16)v1.w;
      *(half8*)&As[row * 40 + kq] = hv;
    }
    // stage B: W1T[0..256)[kk..kk+32) -> Bs
    #pragma unroll
    for (int i = 0; i < 4; ++i) {
      int idx = t + (i << 8);
      int n   = idx >> 2;
      int kq  = (idx & 3) << 3;
      *(half8*)&Bs[n * 40 + kq] = *(const half8*)&W1T[(size_t)n * NF + kk + kq];
    }
    __syncthreads();
    half8 af[4], bf[4];
    #pragma unroll
    for (int mi = 0; mi < 4; ++mi) af[mi] = *(half8*)&As[(mi * 16 + l15) * 40 + q * 8];
    #pragma unroll
    for (int ni = 0; ni < 4; ++ni) bf[ni] = *(half8*)&Bs[(wave * 64 + ni * 16 + l15) * 40 + q * 8];
    #pragma unroll
    for (int mi = 0; mi < 4; ++mi)
      #pragma unroll
      for (int ni = 0; ni < 4; ++ni)
        acc[mi][ni] = __builtin_amdgcn_mfma_f32_16x16x32_f16(af[mi], bf[ni], acc[mi][ni], 0, 0, 0);
  }
  __syncthreads();   // all As/Bs reads complete -> safe to reuse as Hs

  // epilogue 1: bias + relu -> Hs fp16  (C/D: col=lane&15, row=q*4+reg)
  #pragma unroll
  for (int mi = 0; mi < 4; ++mi) {
    #pragma unroll
    for (int ni = 0; ni < 4; ++ni) {
      int ch = wave * 64 + ni * 16 + l15;
      float bb = b1[ch];
      #pragma unroll
      for (int r = 0; r < 4; ++r) {
        int m = mi * 16 + q * 4 + r;
        float v = acc[mi][ni][r] + bb;
        Hs[m * 264 + ch] = (_Float16)(v > 0.f ? v : 0.f);
      }
    }
  }
  __syncthreads();

  // GEMM2: h0[64x64] = Hs[64x256] @ W2 (+b2); wave w -> cols [16w, 16w+16)
  f32x4 acc2[4] = {};
  for (int kt = 0; kt < 8; ++kt) {
    half8 bf2 = *(const half8*)&W2T[(size_t)(wave * 16 + l15) * NH + kt * 32 + q * 8];
    #pragma unroll
    for (int mi = 0; mi < 4; ++mi) {
      half8 af2 = *(half8*)&Hs[(mi * 16 + l15) * 264 + kt * 32 + q * 8];
      acc2[mi] = __builtin_amdgcn_mfma_f32_16x16x32_f16(af2, bf2, acc2[mi], 0, 0, 0);
    }
  }
  int c = wave * 16 + l15;
  float bb2 = b2[c];
  #pragma unroll
  for (int mi = 0; mi < 4; ++mi)
    #pragma unroll
    for (int r = 0; r < 4; ++r) {
      int m = m0 + mi * 16 + q * 4 + r;
      if (m < NN) {
        float hv = acc2[mi][r] + bb2;
        float dv = dinv[m];
        y0[(size_t)m * NC + c] = (_Float16)(dv * hv);
        c0[(size_t)m * NC + c] = (_Float16)(0.1f * dv * hv);
      }
    }
}

// ---------------- APPNP propagation step on y = dinv*h ----------------
// one wave per node; lane = feature. Edge lists are 8-padded with zero-node NN.

__global__ __launch_bounds__(256) void appnp_k(const _Float16* __restrict__ y_in, const _Float16* __restrict__ c0,
                                               _Float16* __restrict__ y_out,
                                               const int* __restrict__ row_ptr, const int* __restrict__ srcS,
                                               const float* __restrict__ amul) {
  int lane = threadIdx.x & 63;
  int node = blockIdx.x * 4 + (threadIdx.x >> 6);
  node = __builtin_amdgcn_readfirstlane(node);   // wave-uniform -> scalar loads
  int beg = row_ptr[node];
  int end = row_ptr[node + 1];
  float a0 = (float)y_in[(size_t)node * NC + lane];   // self-loop
  float a1 = 0.f, a2 = 0.f, a3 = 0.f;
  for (int e = beg; e < end; e += 8) {
    int sj[8];
    #pragma unroll
    for (int j = 0; j < 8; ++j) sj[j] = srcS[e + j];
    float v[8];
    #pragma unroll
    for (int j = 0; j < 8; ++j) v[j] = (float)y_in[(size_t)sj[j] * NC + lane];
    a0 += v[0] + v[4];
    a1 += v[1] + v[5];
    a2 += v[2] + v[6];
    a3 += v[3] + v[7];
  }
  size_t o = (size_t)node * NC + lane;
  y_out[o] = (_Float16)(amul[node] * ((a0 + a1) + (a2 + a3)) + (float)c0[o]);
}

// ---------------- log_softmax (recover h = y * sqrt(deg)) ----------------

__global__ __launch_bounds__(256) void lsm_k(const _Float16* __restrict__ y, const float* __restrict__ dsqrt,
                                             float* __restrict__ out) {
  int lane = threadIdx.x & 63;
  int node = blockIdx.x * 4 + (threadIdx.x >> 6);
  node = __builtin_amdgcn_readfirstlane(node);
  float v = (float)y[(size_t)node * NC + lane] * dsqrt[node];
  float m = v;
  #pragma unroll
  for (int off = 32; off > 0; off >>= 1) m = fmaxf(m, __shfl_xor(m, off, 64));
  float e = expf(v - m);
  float s = e;
  #pragma unroll
  for (int off = 32; off > 0; off >>= 1) s += __shfl_xor(s, off, 64);
  out[(size_t)node * NC + lane] = (v - m) - logf(s);
}

// ---------------- launch ----------------

extern "C" void kernel_launch(void* const* d_in, const int* in_sizes, int n_in,
                              void* d_out, int out_size, void* d_ws, size_t ws_size,
                              hipStream_t stream) {
  (void)in_sizes; (void)n_in; (void)out_size; (void)ws_size;
  const float* x  = (const float*)d_in[0];
  const int*   ei = (const int*)d_in[1];
  const float* W1 = (const float*)d_in[2];
  const float* b1 = (const float*)d_in[3];
  const float* W2 = (const float*)d_in[4];
  const float* b2 = (const float*)d_in[5];
  float* out = (float*)d_out;

  const int* srcI = ei;        // edge_index[0] = message source
  const int* dstI = ei + NE;   // edge_index[1] = aggregation target

  char* p = (char*)d_ws;
  auto carve = [&](size_t bytes) -> void* {
    void* q = (void*)p;
    p += (bytes + 255) & ~(size_t)255;
    return q;
  };
  _Float16* y0   = (_Float16*)carve((size_t)(NN + 1) * NC * 2);
  _Float16* yA   = (_Float16*)carve((size_t)(NN + 1) * NC * 2);
  _Float16* yB   = (_Float16*)carve((size_t)(NN + 1) * NC * 2);
  _Float16* c0   = (_Float16*)carve((size_t)NN * NC * 2);
  _Float16* W1T  = (_Float16*)carve((size_t)NH * NF * 2);
  _Float16* W2T  = (_Float16*)carve((size_t)NC * NH * 2);
  float* deg     = (float*)carve((size_t)NN * 4);
  float* dinv    = (float*)carve((size_t)NN * 4);
  float* dsqrt   = (float*)carve((size_t)NN * 4);
  float* amul    = (float*)carve((size_t)NN * 4);
  int*   row_ptr = (int*)carve((size_t)(NN + 1) * 4);
  int*   fill    = (int*)carve((size_t)NN * 4);
  int*   partial = (int*)carve((size_t)NN * 4);
  int*   bsums   = (int*)carve((size_t)NB * 4);
  int*   boffs   = (int*)carve((size_t)NB * 4);
  int*   srcS    = (int*)carve((size_t)(NE + 8 * NN) * 4);

  init_deg_k <<<NB, 256, 0, stream>>>(deg);
  accum_deg_k<<<(NE + 255) / 256, 256, 0, stream>>>(dstI, deg);
  scan1_k    <<<NB, 256, 0, stream>>>(deg, partial, bsums);
  scan2_k    <<<1, 512, 0, stream>>>(bsums, boffs);
  scan3_k    <<<NB, 256, 0, stream>>>(partial, boffs, deg, row_ptr, fill);
  dinv_k     <<<NB, 256, 0, stream>>>(deg, dinv, dsqrt, amul);
  fill_k     <<<(NE + 255) / 256, 256, 0, stream>>>(dstI, fill, srcI, srcS);
  pad_k      <<<NB, 256, 0, stream>>>(fill, row_ptr, srcS);
  zrow_k     <<<1, 256, 0, stream>>>(y0, yA, yB);
  cvtW1T_k   <<<(NH * NF) / 256, 256, 0, stream>>>(W1, W1T);
  cvtW2T_k   <<<(NC * NH) / 256, 256, 0, stream>>>(W2, W2T);
  mlp_k      <<<(NN + 63) / 64, 256, 0, stream>>>(x, W1T, b1, W2T, b2, dinv, y0, c0);

  const _Float16* yin = y0;
  _Float16* bufs[2] = { yA, yB };
  for (int it = 0; it < KSTEPS; ++it) {
    _Float16* yo = bufs[it & 1];
    appnp_k<<<NN / 4, 256, 0, stream>>>(yin, c0, yo, row_ptr, srcS, amul);
    yin = yo;
  }
  lsm_k<<<NN / 4, 256, 0, stream>>>(yin, dsqrt, out);
}